// Round 1
// baseline (2623.330 us; speedup 1.0000x reference)
//
#include <hip/hip_runtime.h>
#include <cmath>

#define NUM_E 256
#define NUM_G 8
#define EPG 32
#define TOPK 8
#define TOPKG 4

// Block: 256 threads, 32 tokens. GEMM: thread -> 2 expert rows x 16 tokens.
// Gating: wave -> 8 tokens, lane -> 4 experts (from LDS).
__global__ __launch_bounds__(256, 1)
void moe_gate_kernel(const float* __restrict__ hs,
                     const float* __restrict__ wgt,
                     const float* __restrict__ bias,
                     float* __restrict__ out,   // [T*8 idx-as-float][T*8 weights]
                     int T, int H) {
  __shared__ float sfc[32][NUM_E];   // corrected scores (sigmoid + bias), 32 KB

  const int tid  = threadIdx.x;
  const int lane = tid & 63;
  const int wv   = tid >> 6;            // wave id 0..3
  const int tb   = blockIdx.x * 32;     // token base for this block
  if (tb >= T) return;

  // ---------------- GEMM phase ----------------
  const int e0 = (tid & 127) * 2;                                   // experts e0, e0+1
  const int t0 = __builtin_amdgcn_readfirstlane((tid >> 7) * 16);   // wave-uniform token offset

  const float* __restrict__ hp  = hs + (size_t)(tb + t0) * H;       // uniform -> s_load
  const float* __restrict__ w0p = wgt + (size_t)e0 * H;
  const float* __restrict__ w1p = w0p + H;

  float a0[16], b0[16], a1[16], b1[16];
#pragma unroll
  for (int i = 0; i < 16; ++i) { a0[i] = 0.f; b0[i] = 0.f; a1[i] = 0.f; b1[i] = 0.f; }

  for (int k = 0; k < H; k += 4) {
    const float4 w0 = *(const float4*)(w0p + k);
    const float4 w1 = *(const float4*)(w1p + k);
#pragma unroll
    for (int i = 0; i < 16; ++i) {
      const float4 h = *(const float4*)(hp + (size_t)i * H + k);  // wave-uniform address
      a0[i] = fmaf(h.x, w0.x, fmaf(h.y, w0.y, a0[i]));
      b0[i] = fmaf(h.z, w0.z, fmaf(h.w, w0.w, b0[i]));
      a1[i] = fmaf(h.x, w1.x, fmaf(h.y, w1.y, a1[i]));
      b1[i] = fmaf(h.z, w1.z, fmaf(h.w, w1.w, b1[i]));
    }
  }

  const float bias0 = bias[e0];
  const float bias1 = bias[e0 + 1];
#pragma unroll
  for (int i = 0; i < 16; ++i) {
    const float l0 = a0[i] + b0[i];
    const float l1 = a1[i] + b1[i];
    const float s0 = 1.f / (1.f + expf(-l0));
    const float s1 = 1.f / (1.f + expf(-l1));
    *(float2*)&sfc[t0 + i][e0] = make_float2(s0 + bias0, s1 + bias1);
  }
  __syncthreads();

  // ---------------- Gating phase ----------------
  // lane -> experts 4*lane .. 4*lane+3 ; group g = lane>>3 (4 consecutive experts share a group)
  const float4 bias4 = *(const float4*)(bias + 4 * lane);
  const int g = lane >> 3;
  const float NEG_INF = -__builtin_inff();

  for (int it = 0; it < 8; ++it) {
    const int t = wv * 8 + it;
    const float4 s4 = *(const float4*)&sfc[t][4 * lane];

    // per-lane top-2 of 4 corrected scores
    float m1 = s4.x, m2 = NEG_INF;
    if (s4.y > m1) { m2 = m1; m1 = s4.y; } else if (s4.y > m2) m2 = s4.y;
    if (s4.z > m1) { m2 = m1; m1 = s4.z; } else if (s4.z > m2) m2 = s4.z;
    if (s4.w > m1) { m2 = m1; m1 = s4.w; } else if (s4.w > m2) m2 = s4.w;
    // merge across the 8 lanes of this group (xor 1,2,4 stays in-group)
#pragma unroll
    for (int m = 1; m <= 4; m <<= 1) {
      const float o1 = __shfl_xor(m1, m);
      const float o2 = __shfl_xor(m2, m);
      const float nm1 = fmaxf(m1, o1);
      const float nm2 = fmaxf(fminf(m1, o1), fmaxf(m2, o2));
      m1 = nm1; m2 = nm2;
    }
    const float gs = m1 + m2;   // group score (sum of top-2)

    // gather all 8 group scores to every lane
    float gsv[8];
#pragma unroll
    for (int j = 0; j < 8; ++j) gsv[j] = __shfl(gs, j * 8);

    // top-4 groups, tie -> lowest group index (matches lax.top_k)
    unsigned gm = 0;
#pragma unroll
    for (int r = 0; r < TOPKG; ++r) {
      float best = NEG_INF; int bj = 0;
#pragma unroll
      for (int j = 0; j < 8; ++j) {
        const bool avail = !((gm >> j) & 1u);
        if (avail && gsv[j] > best) { best = gsv[j]; bj = j; }
      }
      gm |= 1u << bj;
    }
    const bool allowed = (gm >> g) & 1u;

    // masked scores (exactly 0.0 for disallowed, like the reference)
    float v0 = allowed ? s4.x : 0.f;
    float v1 = allowed ? s4.y : 0.f;
    float v2 = allowed ? s4.z : 0.f;
    float v3 = allowed ? s4.w : 0.f;

    float sumw = 0.f;
    int myidx = 0; float myraw = 0.f;
#pragma unroll
    for (int r = 0; r < TOPK; ++r) {
      // local argmax, lowest index on tie
      float bv = v0; int bj = 0;
      if (v1 > bv) { bv = v1; bj = 1; }
      if (v2 > bv) { bv = v2; bj = 2; }
      if (v3 > bv) { bv = v3; bj = 3; }
      int bidx = 4 * lane + bj;
      // wave argmax with lowest-global-index tie-break
#pragma unroll
      for (int m = 1; m < 64; m <<= 1) {
        const float ov = __shfl_xor(bv, m);
        const int   oi = __shfl_xor(bidx, m);
        if (ov > bv || (ov == bv && oi < bidx)) { bv = ov; bidx = oi; }
      }
      // bidx is wave-uniform; recover UNcorrected score = sfc - bias from owner lane
      const int oj = bidx & 3;
      const float cand = (oj == 0) ? (s4.x - bias4.x)
                       : (oj == 1) ? (s4.y - bias4.y)
                       : (oj == 2) ? (s4.z - bias4.z)
                       :             (s4.w - bias4.w);
      const float raw = __shfl(cand, bidx >> 2);
      sumw += raw;
      if (lane == r) { myidx = bidx; myraw = raw; }
      if (lane == (bidx >> 2)) {
        if      (oj == 0) v0 = NEG_INF;
        else if (oj == 1) v1 = NEG_INF;
        else if (oj == 2) v2 = NEG_INF;
        else              v3 = NEG_INF;
      }
    }

    if (lane < TOPK) {
      const size_t gt = (size_t)(tb + t);
      out[gt * TOPK + lane] = (float)myidx;                                  // idx as float
      out[(size_t)T * TOPK + gt * TOPK + lane] = myraw / (sumw + 1e-20f) * 2.5f;
    }
  }
}

extern "C" void kernel_launch(void* const* d_in, const int* in_sizes, int n_in,
                              void* d_out, int out_size, void* d_ws, size_t ws_size,
                              hipStream_t stream) {
  const float* hs   = (const float*)d_in[0];
  const float* wgt  = (const float*)d_in[1];
  const float* bias = (const float*)d_in[2];
  float* out = (float*)d_out;

  const int E = in_sizes[2];        // 256
  const int H = in_sizes[1] / E;    // 7168
  const int T = in_sizes[0] / H;    // 8192

  dim3 grid(T / 32), block(256);
  hipLaunchKernelGGL(moe_gate_kernel, grid, block, 0, stream, hs, wgt, bias, out, T, H);
}

// Round 4
// 551.023 us; speedup vs baseline: 4.7608x; 4.7608x over previous
//
#include <hip/hip_runtime.h>
#include <cmath>

typedef __attribute__((ext_vector_type(8))) _Float16 half8;
typedef __attribute__((ext_vector_type(4))) float f32x4;

#define HH 7168
#define NE 256
#define NQ 224        // K32 chunks
#define NITER 56      // BK=128 iterations
#define TOPK 8
#define TOPKG 4

#define C1 (1.f/2048.f)       // 2^-11
#define C2 (1.f/4194304.f)    // 2^-22

// exact 3-level f16 split: x = h + m*2^-11 + l*2^-22, residual ~2^-34|x|.
// m,l pre-scaled into f16 normal range.
__device__ __forceinline__ void split3(float x, unsigned short& h, unsigned short& m, unsigned short& l){
  const _Float16 hh = (_Float16)x;
  const float r1 = x - (float)hh;                    // exact
  const _Float16 mm = (_Float16)(r1 * 2048.f);
  const float r2 = r1 - (float)mm * C1;              // exact (cancellation)
  const _Float16 ll = (_Float16)(r2 * 4194304.f);
  h = __builtin_bit_cast(unsigned short, hh);
  m = __builtin_bit_cast(unsigned short, mm);
  l = __builtin_bit_cast(unsigned short, ll);
}

// Pre-split W into 3 f16 levels in exact MFMA B-fragment order:
// K32-chunk q, expert-tile nt, lane L holds B[k=32q+8*(L>>4)+j][n=16nt+(L&15)], j=0..7.
// slot = (q*16+nt)*64+L (8 ushorts per slot).
__global__ __launch_bounds__(256) void prep_w(const float* __restrict__ wgt,
                                              unsigned short* __restrict__ bh,
                                              unsigned short* __restrict__ bm,
                                              unsigned short* __restrict__ bl){
  const int g = blockIdx.x*256 + threadIdx.x;     // NE*HH/4 threads
  const int e = g / (HH/4);
  const int k0 = (g - e*(HH/4))*4;
  const float4 wv = *(const float4*)(wgt + (size_t)e*HH + k0);
  const float v[4] = {wv.x, wv.y, wv.z, wv.w};
  unsigned short h4[4], m4[4], l4[4];
#pragma unroll
  for(int i=0;i<4;i++) split3(v[i], h4[i], m4[i], l4[i]);
  const int q = k0>>5, lq = (k0>>3)&3, j0 = k0&7;  // j0 in {0,4}
  const int nt = e>>4, n16 = e&15;
  const int L = lq*16 + n16;
  const size_t base = ((size_t)(q*16+nt)*64 + L)*8 + j0;
  *(ushort4*)(bh+base) = make_ushort4(h4[0],h4[1],h4[2],h4[3]);
  *(ushort4*)(bm+base) = make_ushort4(m4[0],m4[1],m4[2],m4[3]);
  *(ushort4*)(bl+base) = make_ushort4(l4[0],l4[1],l4[2],l4[3]);
}

// A-staging: plain row-major [tok][k] per level, stride 136 ushorts (128 + 8 pad).
__device__ __forceinline__ void stageA(unsigned short* alds, int buf, int tok, int k0, const float4* ga){
#pragma unroll
  for(int u=0;u<4;u++){
    const float vv[4] = {ga[u].x, ga[u].y, ga[u].z, ga[u].w};
    unsigned short h4[4], m4[4], l4[4];
#pragma unroll
    for(int p=0;p<4;p++) split3(vv[p], h4[p], m4[p], l4[p]);
    const int ui = tok*136 + k0 + 4*u;
    *(ushort4*)&alds[(buf*3+0)*4352 + ui] = make_ushort4(h4[0],h4[1],h4[2],h4[3]);
    *(ushort4*)&alds[(buf*3+1)*4352 + ui] = make_ushort4(m4[0],m4[1],m4[2],m4[3]);
    *(ushort4*)&alds[(buf*3+2)*4352 + ui] = make_ushort4(l4[0],l4[1],l4[2],l4[3]);
  }
}

// Block: 32 tokens x 256 experts; wave w -> experts 64w..64w+63 (nt 0..3), mt in {0,1}.
__global__ __launch_bounds__(256,1)
void moe_gate(const float* __restrict__ hs,
              const unsigned short* __restrict__ bhp,
              const unsigned short* __restrict__ bmp,
              const unsigned short* __restrict__ blp,
              const float* __restrict__ bias,
              float* __restrict__ out, int T){
  __shared__ __align__(16) unsigned char smem[52224];  // A dbuf (3 lvl x 32x136 x2) / sfc union
  unsigned short* alds = (unsigned short*)smem;
  float (*sfc)[NE] = (float (*)[NE])smem;

  const int tid = threadIdx.x, lane = tid&63, w = tid>>6;
  const int tb = blockIdx.x*32;

  const half8* __restrict__ bhv = (const half8*)bhp;
  const half8* __restrict__ bmv = (const half8*)bmp;
  const half8* __restrict__ blv = (const half8*)blp;

  float biasv[4];
#pragma unroll
  for(int nt=0;nt<4;nt++) biasv[nt] = bias[w*64 + nt*16 + (lane&15)];

  f32x4 ksum[2][4], kcmp[2][4];
#pragma unroll
  for(int mt=0;mt<2;mt++)
#pragma unroll
    for(int nt=0;nt<4;nt++){ ksum[mt][nt] = f32x4{0,0,0,0}; kcmp[mt][nt] = f32x4{0,0,0,0}; }

  const int tokS = tid>>3, k0S = (tid&7)*16;
  const float* agp = hs + (size_t)(tb+tokS)*HH + k0S;

  { // stage iter 0 into buf 0
    float4 ga[4];
#pragma unroll
    for(int u=0;u<4;u++) ga[u] = *(const float4*)(agp + 4*u);
    stageA(alds, 0, tokS, k0S, ga);
  }
  // prefetch B fragments for q=0
  half8 Bh[4], Bm[4], Bl[4];
#pragma unroll
  for(int nt=0;nt<4;nt++){
    const int slot = (w*4 + nt)*64 + lane;
    Bh[nt] = bhv[slot]; Bm[nt] = bmv[slot]; Bl[nt] = blv[slot];
  }
  __syncthreads();

  for(int i=0;i<NITER;i++){
    const int cur = i&1, nb = cur^1;
    float4 ga[4];
    if(i+1<NITER){
      const float* ap = agp + (size_t)(i+1)*128;
#pragma unroll
      for(int u=0;u<4;u++) ga[u] = *(const float4*)(ap + 4*u);
    }
    // per-window accumulators (3 scale classes)
    f32x4 a0[2][4], a1[2][4], a2[2][4];
#pragma unroll
    for(int mt=0;mt<2;mt++)
#pragma unroll
      for(int nt=0;nt<4;nt++){ a0[mt][nt]=f32x4{0,0,0,0}; a1[mt][nt]=f32x4{0,0,0,0}; a2[mt][nt]=f32x4{0,0,0,0}; }

#pragma unroll
    for(int s=0;s<4;s++){
      const int q = i*4+s;
      half8 ah[2], am[2], al[2];
#pragma unroll
      for(int mt=0;mt<2;mt++){
        const int off = (mt*16 + (lane&15))*136 + 32*s + 8*(lane>>4);
        ah[mt] = *(const half8*)&alds[(cur*3+0)*4352 + off];
        am[mt] = *(const half8*)&alds[(cur*3+1)*4352 + off];
        al[mt] = *(const half8*)&alds[(cur*3+2)*4352 + off];
      }
      half8 BhN[4], BmN[4], BlN[4];
      const bool more = (q+1 < NQ);
      if(more){
#pragma unroll
        for(int nt=0;nt<4;nt++){
          const int slot = ((q+1)*16 + w*4 + nt)*64 + lane;
          BhN[nt] = bhv[slot]; BmN[nt] = bmv[slot]; BlN[nt] = blv[slot];
        }
      }
#pragma unroll
      for(int mt=0;mt<2;mt++)
#pragma unroll
        for(int nt=0;nt<4;nt++){
          a0[mt][nt] = __builtin_amdgcn_mfma_f32_16x16x32_f16(ah[mt], Bh[nt], a0[mt][nt], 0,0,0);
          a1[mt][nt] = __builtin_amdgcn_mfma_f32_16x16x32_f16(ah[mt], Bm[nt], a1[mt][nt], 0,0,0);
          a1[mt][nt] = __builtin_amdgcn_mfma_f32_16x16x32_f16(am[mt], Bh[nt], a1[mt][nt], 0,0,0);
          a2[mt][nt] = __builtin_amdgcn_mfma_f32_16x16x32_f16(ah[mt], Bl[nt], a2[mt][nt], 0,0,0);
          a2[mt][nt] = __builtin_amdgcn_mfma_f32_16x16x32_f16(al[mt], Bh[nt], a2[mt][nt], 0,0,0);
          a2[mt][nt] = __builtin_amdgcn_mfma_f32_16x16x32_f16(am[mt], Bm[nt], a2[mt][nt], 0,0,0);
        }
      if(more){
#pragma unroll
        for(int nt=0;nt<4;nt++){ Bh[nt]=BhN[nt]; Bm[nt]=BmN[nt]; Bl[nt]=BlN[nt]; }
      }
    }
    if(i+1<NITER) stageA(alds, nb, tokS, k0S, ga);
    // Kahan flush of this 128-k window
#pragma unroll
    for(int mt=0;mt<2;mt++)
#pragma unroll
      for(int nt=0;nt<4;nt++)
#pragma unroll
        for(int r=0;r<4;r++){
          const float v = a0[mt][nt][r] + a1[mt][nt][r]*C1 + a2[mt][nt][r]*C2;
          const float y = v - kcmp[mt][nt][r];
          const float t = ksum[mt][nt][r] + y;
          kcmp[mt][nt][r] = (t - ksum[mt][nt][r]) - y;
          ksum[mt][nt][r] = t;
        }
    __syncthreads();
  }

  // epilogue: C layout col=lane&15 (expert), row=(lane>>4)*4+r (token)
#pragma unroll
  for(int mt=0;mt<2;mt++)
#pragma unroll
    for(int nt=0;nt<4;nt++)
#pragma unroll
      for(int r=0;r<4;r++){
        const int tok = mt*16 + (lane>>4)*4 + r;
        const int e = w*64 + nt*16 + (lane&15);
        const float lg = ksum[mt][nt][r] - kcmp[mt][nt][r];
        const float sg = 1.f/(1.f + expf(-lg));
        sfc[tok][e] = sg + biasv[nt];
      }
  __syncthreads();

  // ---------------- Gating phase (verified in R1) ----------------
  const float4 bias4 = *(const float4*)(bias + 4*lane);
  const int g = lane >> 3;
  const float NEG_INF = -__builtin_inff();

  for (int it = 0; it < 8; ++it) {
    const int t = w * 8 + it;
    const float4 s4 = *(const float4*)&sfc[t][4*lane];

    float m1 = s4.x, m2 = NEG_INF;
    if (s4.y > m1) { m2 = m1; m1 = s4.y; } else if (s4.y > m2) m2 = s4.y;
    if (s4.z > m1) { m2 = m1; m1 = s4.z; } else if (s4.z > m2) m2 = s4.z;
    if (s4.w > m1) { m2 = m1; m1 = s4.w; } else if (s4.w > m2) m2 = s4.w;
#pragma unroll
    for (int m = 1; m <= 4; m <<= 1) {
      const float o1 = __shfl_xor(m1, m);
      const float o2 = __shfl_xor(m2, m);
      const float nm1 = fmaxf(m1, o1);
      const float nm2 = fmaxf(fminf(m1, o1), fmaxf(m2, o2));
      m1 = nm1; m2 = nm2;
    }
    const float gs = m1 + m2;

    float gsv[8];
#pragma unroll
    for (int j = 0; j < 8; ++j) gsv[j] = __shfl(gs, j * 8);

    unsigned gm = 0;
#pragma unroll
    for (int r = 0; r < TOPKG; ++r) {
      float best = NEG_INF; int bj = 0;
#pragma unroll
      for (int j = 0; j < 8; ++j) {
        const bool avail = !((gm >> j) & 1u);
        if (avail && gsv[j] > best) { best = gsv[j]; bj = j; }
      }
      gm |= 1u << bj;
    }
    const bool allowed = (gm >> g) & 1u;

    float v0 = allowed ? s4.x : 0.f;
    float v1 = allowed ? s4.y : 0.f;
    float v2 = allowed ? s4.z : 0.f;
    float v3 = allowed ? s4.w : 0.f;

    float sumw = 0.f;
    int myidx = 0; float myraw = 0.f;
#pragma unroll
    for (int r = 0; r < TOPK; ++r) {
      float bv = v0; int bj = 0;
      if (v1 > bv) { bv = v1; bj = 1; }
      if (v2 > bv) { bv = v2; bj = 2; }
      if (v3 > bv) { bv = v3; bj = 3; }
      int bidx = 4 * lane + bj;
#pragma unroll
      for (int m = 1; m < 64; m <<= 1) {
        const float ov = __shfl_xor(bv, m);
        const int   oi = __shfl_xor(bidx, m);
        if (ov > bv || (ov == bv && oi < bidx)) { bv = ov; bidx = oi; }
      }
      const int oj = bidx & 3;
      const float cand = (oj == 0) ? (s4.x - bias4.x)
                       : (oj == 1) ? (s4.y - bias4.y)
                       : (oj == 2) ? (s4.z - bias4.z)
                       :             (s4.w - bias4.w);
      const float raw = __shfl(cand, bidx >> 2);
      sumw += raw;
      if (lane == r) { myidx = bidx; myraw = raw; }
      if (lane == (bidx >> 2)) {
        if      (oj == 0) v0 = NEG_INF;
        else if (oj == 1) v1 = NEG_INF;
        else if (oj == 2) v2 = NEG_INF;
        else              v3 = NEG_INF;
      }
    }

    if (lane < TOPK) {
      const size_t gt = (size_t)(tb + t);
      out[gt * TOPK + lane] = (float)myidx;
      out[(size_t)T * TOPK + gt * TOPK + lane] = myraw / (sumw + 1e-20f) * 2.5f;
    }
  }
}

extern "C" void kernel_launch(void* const* d_in, const int* in_sizes, int n_in,
                              void* d_out, int out_size, void* d_ws, size_t ws_size,
                              hipStream_t stream) {
  const float* hs   = (const float*)d_in[0];
  const float* wgt  = (const float*)d_in[1];
  const float* bias = (const float*)d_in[2];
  float* out = (float*)d_out;

  const int T = in_sizes[0] / HH;   // 8192

  unsigned short* bh = (unsigned short*)d_ws;
  unsigned short* bm = bh + (size_t)NE*HH;
  unsigned short* bl = bm + (size_t)NE*HH;

  hipLaunchKernelGGL(prep_w, dim3(NE*HH/4/256), dim3(256), 0, stream, wgt, bh, bm, bl);
  hipLaunchKernelGGL(moe_gate, dim3(T/32), dim3(256), 0, stream, hs, bh, bm, bl, bias, out, T);
}

// Round 5
// 499.472 us; speedup vs baseline: 5.2522x; 1.1032x over previous
//
#include <hip/hip_runtime.h>
#include <cmath>

typedef __attribute__((ext_vector_type(8))) _Float16 half8;
typedef __attribute__((ext_vector_type(8))) unsigned short ushort8;
typedef __attribute__((ext_vector_type(4))) float f32x4;

#define HH 7168
#define NE 256
#define NQ 224        // K32 chunks
#define NITER 56      // BK=128 iterations
#define TOPK 8
#define TOPKG 4
#define WSC 1024.f
#define INV_WS (1.f/1024.f)
#define C1 (1.f/2048.f)       // 2^-11
#define C2 (1.f/4194304.f)    // 2^-22

// 2-level f16 split: x = h + m*2^-11, residual ~2^-25|x|
__device__ __forceinline__ void split2(float x, unsigned short& h, unsigned short& m){
  const _Float16 hh = (_Float16)x;
  const float r = x - (float)hh;                 // exact
  const _Float16 mm = (_Float16)(r * 2048.f);
  h = __builtin_bit_cast(unsigned short, hh);
  m = __builtin_bit_cast(unsigned short, mm);
}

// W*1024 -> (h,m) f16 in MFMA B-fragment order, coalesced writes.
// slot(q,nt,L) holds B[k=32q+8(L>>4)+j][e=16nt+(L&15)], j=0..7.
__global__ __launch_bounds__(256) void prep_w(const float* __restrict__ wgt,
                                              unsigned short* __restrict__ bh,
                                              unsigned short* __restrict__ bm){
  const int b = blockIdx.x;                 // 896 = 16 nt * 56 q-groups
  const int nt = b & 15, qb = (b >> 4) * 4;
  const int w = threadIdx.x >> 6, L = threadIdx.x & 63;
  const int q = qb + w;
  const int e = nt*16 + (L & 15);
  const int k0 = 32*q + 8*(L >> 4);
  const float4 a0 = *(const float4*)(wgt + (size_t)e*HH + k0);
  const float4 a1 = *(const float4*)(wgt + (size_t)e*HH + k0 + 4);
  const float v[8] = {a0.x,a0.y,a0.z,a0.w,a1.x,a1.y,a1.z,a1.w};
  ushort8 h8, m8;
#pragma unroll
  for(int j=0;j<8;j++){ unsigned short hh,mm; split2(v[j]*WSC, hh, mm); h8[j]=hh; m8[j]=mm; }
  const size_t base = ((size_t)(q*16+nt)*64 + L)*8;
  *(ushort8*)(bh+base) = h8;
  *(ushort8*)(bm+base) = m8;
}

// GEMM: block = 64 tokens x 128 experts (slice), 512 thr / 8 waves, wave = 2mt x 2nt tiles.
// XCD swizzle: slice=(b>>2)&1 so each 3.67MB B-slice stays L2-resident on its 4 XCDs.
#define STIDX(buf,lvl,mt,q,row) (((((buf)*2+(lvl))*16 + (mt)*4 + (q))*64 + (row))*8)
__global__ __launch_bounds__(512,2)
void gemm(const float* __restrict__ hs,
          const unsigned short* __restrict__ bhp,
          const unsigned short* __restrict__ bmp,
          float* __restrict__ lgout){
  __shared__ __align__(16) unsigned short alds[32768];   // 64 KB: 2buf x 2lvl x 4mt x 4q x 64rows x 8

  const int tid = threadIdx.x, lane = tid & 63, w = tid >> 6;
  const int b = blockIdx.x;
  const int slice = (b >> 2) & 1;
  const int tg = (b >> 3)*4 + (b & 3);     // 0..127
  const int tb = tg*64, eb = slice*128;
  const int mtp = w >> 2, ntp = w & 3;     // wave tiles: mt = 2mtp+{0,1}, nt = 2ntp+{0,1}

  const half8* __restrict__ bhv = (const half8*)bhp;
  const half8* __restrict__ bmv = (const half8*)bmp;

  f32x4 ksum[2][2], kcmp[2][2];
#pragma unroll
  for(int a=0;a<2;a++)
#pragma unroll
    for(int c=0;c<2;c++){ ksum[a][c]=f32x4{0,0,0,0}; kcmp[a][c]=f32x4{0,0,0,0}; }

  // staging: thread -> token tid>>3, 16 ks at (tid&7)*16
  const int tokS = tid >> 3, cS = tid & 7;
  const int mtS = tokS >> 4, m16S = tokS & 15, qS = cS >> 1;
  const int rowA = (cS & 1)*32 + m16S;      // lq = (cS&1)*2
  const float* agp = hs + (size_t)(tb + tokS)*HH + cS*16;

  float4 ga[4];
#pragma unroll
  for(int u=0;u<4;u++) ga[u] = *(const float4*)(agp + 4*u);

  auto stage = [&](int buf){
    unsigned short h[16], m[16];
    const float* gv = (const float*)ga;
#pragma unroll
    for(int p=0;p<16;p++) split2(gv[p], h[p], m[p]);
#pragma unroll
    for(int lvl=0; lvl<2; lvl++){
      const unsigned short* src = lvl ? m : h;
      ushort8 lo, hi;
#pragma unroll
      for(int j=0;j<8;j++){ lo[j]=src[j]; hi[j]=src[8+j]; }
      const int ia = STIDX(buf,lvl,mtS,qS,rowA);
      *(ushort8*)&alds[ia]        = lo;   // row rowA   (j = k_in&7, k_in 0..7 of its lq)
      *(ushort8*)&alds[ia + 128]  = hi;   // row rowA+16
    }
  };

  stage(0);
  half8 Bh[2], Bm[2];
#pragma unroll
  for(int ntl=0;ntl<2;ntl++){
    const int slot = ((0*16 + slice*8 + ntp*2 + ntl)*64 + lane);
    Bh[ntl] = bhv[slot]; Bm[ntl] = bmv[slot];
  }
  __syncthreads();

  for(int i=0;i<NITER;i++){
    const int cur = i & 1, nb = cur ^ 1;
    if(i+1 < NITER){
      const float* ap = agp + (size_t)(i+1)*128;
#pragma unroll
      for(int u=0;u<4;u++) ga[u] = *(const float4*)(ap + 4*u);
    }
    f32x4 c0[2][2], c1[2][2], c2[2][2];
#pragma unroll
    for(int a=0;a<2;a++)
#pragma unroll
      for(int c=0;c<2;c++){ c0[a][c]=f32x4{0,0,0,0}; c1[a][c]=f32x4{0,0,0,0}; c2[a][c]=f32x4{0,0,0,0}; }

#pragma unroll
    for(int s=0;s<4;s++){
      const int q = i*4 + s;
      half8 ah[2], am[2];
#pragma unroll
      for(int mtl=0;mtl<2;mtl++){
        const int mt = mtp*2 + mtl;
        ah[mtl] = *(const half8*)&alds[STIDX(cur,0,mt,s,lane)];
        am[mtl] = *(const half8*)&alds[STIDX(cur,1,mt,s,lane)];
      }
      half8 BhN[2], BmN[2];
      const bool more = (q+1 < NQ);
      if(more){
#pragma unroll
        for(int ntl=0;ntl<2;ntl++){
          const int slot = (((q+1)*16 + slice*8 + ntp*2 + ntl)*64 + lane);
          BhN[ntl] = bhv[slot]; BmN[ntl] = bmv[slot];
        }
      }
#pragma unroll
      for(int mtl=0;mtl<2;mtl++)
#pragma unroll
        for(int ntl=0;ntl<2;ntl++){
          c0[mtl][ntl] = __builtin_amdgcn_mfma_f32_16x16x32_f16(ah[mtl], Bh[ntl], c0[mtl][ntl], 0,0,0);
          c1[mtl][ntl] = __builtin_amdgcn_mfma_f32_16x16x32_f16(ah[mtl], Bm[ntl], c1[mtl][ntl], 0,0,0);
          c1[mtl][ntl] = __builtin_amdgcn_mfma_f32_16x16x32_f16(am[mtl], Bh[ntl], c1[mtl][ntl], 0,0,0);
          c2[mtl][ntl] = __builtin_amdgcn_mfma_f32_16x16x32_f16(am[mtl], Bm[ntl], c2[mtl][ntl], 0,0,0);
        }
      if(more){
#pragma unroll
        for(int ntl=0;ntl<2;ntl++){ Bh[ntl]=BhN[ntl]; Bm[ntl]=BmN[ntl]; }
      }
    }
    if(i+1 < NITER) stage(nb);
    // Kahan flush of this 128-k window
#pragma unroll
    for(int a=0;a<2;a++)
#pragma unroll
      for(int c=0;c<2;c++)
#pragma unroll
        for(int r=0;r<4;r++){
          const float v = c0[a][c][r] + c1[a][c][r]*C1 + c2[a][c][r]*C2;
          const float y = v - kcmp[a][c][r];
          const float t = ksum[a][c][r] + y;
          kcmp[a][c][r] = (t - ksum[a][c][r]) - y;
          ksum[a][c][r] = t;
        }
    __syncthreads();
  }

  // epilogue: C layout col=lane&15 (expert), row=(lane>>4)*4+r (token); undo W scale
#pragma unroll
  for(int mtl=0;mtl<2;mtl++)
#pragma unroll
    for(int ntl=0;ntl<2;ntl++)
#pragma unroll
      for(int r=0;r<4;r++){
        const int tok = (mtp*2+mtl)*16 + (lane>>4)*4 + r;
        const int e = (ntp*2+ntl)*16 + (lane&15);
        const float lg = (ksum[mtl][ntl][r] - kcmp[mtl][ntl][r]) * INV_WS;
        lgout[(size_t)(tb+tok)*NE + eb + e] = lg;
      }
}

// Gating (R1/R4-verified flow), reading logits from global scratch.
__global__ __launch_bounds__(256)
void gate(const float* __restrict__ lg, const float* __restrict__ bias,
          float* __restrict__ out, int T){
  const int tid = threadIdx.x, lane = tid & 63, wv = tid >> 6;
  const int tb = blockIdx.x*32;
  const float4 bias4 = *(const float4*)(bias + 4*lane);
  const int g = lane >> 3;
  const float NEG_INF = -__builtin_inff();

  for (int it = 0; it < 8; ++it) {
    const int t = tb + wv*8 + it;
    const float4 l4 = *(const float4*)(lg + (size_t)t*NE + 4*lane);
    float4 r4;   // uncorrected sigmoid scores
    r4.x = 1.f/(1.f + expf(-l4.x));
    r4.y = 1.f/(1.f + expf(-l4.y));
    r4.z = 1.f/(1.f + expf(-l4.z));
    r4.w = 1.f/(1.f + expf(-l4.w));
    float4 s4;   // corrected
    s4.x = r4.x + bias4.x; s4.y = r4.y + bias4.y;
    s4.z = r4.z + bias4.z; s4.w = r4.w + bias4.w;

    float m1 = s4.x, m2 = NEG_INF;
    if (s4.y > m1) { m2 = m1; m1 = s4.y; } else if (s4.y > m2) m2 = s4.y;
    if (s4.z > m1) { m2 = m1; m1 = s4.z; } else if (s4.z > m2) m2 = s4.z;
    if (s4.w > m1) { m2 = m1; m1 = s4.w; } else if (s4.w > m2) m2 = s4.w;
#pragma unroll
    for (int m = 1; m <= 4; m <<= 1) {
      const float o1 = __shfl_xor(m1, m);
      const float o2 = __shfl_xor(m2, m);
      const float nm1 = fmaxf(m1, o1);
      const float nm2 = fmaxf(fminf(m1, o1), fmaxf(m2, o2));
      m1 = nm1; m2 = nm2;
    }
    const float gs = m1 + m2;

    float gsv[8];
#pragma unroll
    for (int j = 0; j < 8; ++j) gsv[j] = __shfl(gs, j * 8);

    unsigned gm = 0;
#pragma unroll
    for (int r = 0; r < TOPKG; ++r) {
      float best = NEG_INF; int bj = 0;
#pragma unroll
      for (int j = 0; j < 8; ++j) {
        const bool avail = !((gm >> j) & 1u);
        if (avail && gsv[j] > best) { best = gsv[j]; bj = j; }
      }
      gm |= 1u << bj;
    }
    const bool allowed = (gm >> g) & 1u;

    float v0 = allowed ? s4.x : 0.f;
    float v1 = allowed ? s4.y : 0.f;
    float v2 = allowed ? s4.z : 0.f;
    float v3 = allowed ? s4.w : 0.f;

    float sumw = 0.f;
    int myidx = 0; float myraw = 0.f;
#pragma unroll
    for (int r = 0; r < TOPK; ++r) {
      float bv = v0; int bj = 0;
      if (v1 > bv) { bv = v1; bj = 1; }
      if (v2 > bv) { bv = v2; bj = 2; }
      if (v3 > bv) { bv = v3; bj = 3; }
      int bidx = 4 * lane + bj;
#pragma unroll
      for (int m = 1; m < 64; m <<= 1) {
        const float ov = __shfl_xor(bv, m);
        const int   oi = __shfl_xor(bidx, m);
        if (ov > bv || (ov == bv && oi < bidx)) { bv = ov; bidx = oi; }
      }
      const int oj = bidx & 3;
      const float cand = (oj == 0) ? r4.x
                       : (oj == 1) ? r4.y
                       : (oj == 2) ? r4.z
                       :             r4.w;
      const float raw = __shfl(cand, bidx >> 2);
      sumw += raw;
      if (lane == r) { myidx = bidx; myraw = raw; }
      if (lane == (bidx >> 2)) {
        if      (oj == 0) v0 = NEG_INF;
        else if (oj == 1) v1 = NEG_INF;
        else if (oj == 2) v2 = NEG_INF;
        else              v3 = NEG_INF;
      }
    }

    if (lane < TOPK) {
      out[(size_t)t * TOPK + lane] = (float)myidx;
      out[(size_t)T * TOPK + (size_t)t * TOPK + lane] = myraw / (sumw + 1e-20f) * 2.5f;
    }
  }
}

extern "C" void kernel_launch(void* const* d_in, const int* in_sizes, int n_in,
                              void* d_out, int out_size, void* d_ws, size_t ws_size,
                              hipStream_t stream) {
  const float* hs   = (const float*)d_in[0];
  const float* wgt  = (const float*)d_in[1];
  const float* bias = (const float*)d_in[2];
  float* out = (float*)d_out;

  const int T = in_sizes[0] / HH;   // 8192

  unsigned short* bh = (unsigned short*)d_ws;
  unsigned short* bm = bh + (size_t)NE*HH;
  float* lgbuf = (float*)(bm + (size_t)NE*HH);   // 8.4 MB; total ws use 15.7 MB

  hipLaunchKernelGGL(prep_w, dim3(896), dim3(256), 0, stream, wgt, bh, bm);
  hipLaunchKernelGGL(gemm,   dim3(256), dim3(512), 0, stream, hs, bh, bm, lgbuf);
  hipLaunchKernelGGL(gate,   dim3(T/32), dim3(256), 0, stream, lgbuf, bias, out, T);
}